// Round 20
// baseline (71.931 us; speedup 1.0000x reference)
//
#include <hip/hip_runtime.h>
#include <hip/hip_bf16.h>

// Problem constants (fixed by setup_inputs)
#define NB    16
#define NC    1024
#define NF    4096
#define NFINE (NB*NF)     // 65536
#define CIN   256
#define CSKIP 128
#define KH    (CIN+CSKIP) // 384
#define CMID  256
#define COUT  256

typedef __attribute__((ext_vector_type(8))) short short8;
typedef __attribute__((ext_vector_type(4))) float f32x4;
typedef __attribute__((ext_vector_type(4))) unsigned int u32x4;

__device__ __forceinline__ float bf2f(short s) {
    return __uint_as_float(((unsigned)(unsigned short)s) << 16);
}

// ---------------- K0: bin (blocks 0..15) + prep (blocks 16..655) ----------------
__global__ __launch_bounds__(256)
void binprep_kernel(const float* __restrict__ pos,
                    float* __restrict__ gp, int* __restrict__ gcs,
                    const float* __restrict__ W1, const float* __restrict__ W2,
                    __hip_bfloat16* __restrict__ W1at,
                    __hip_bfloat16* __restrict__ imgG,
                    __hip_bfloat16* __restrict__ img2)
{
    __shared__ int cnt[512];
    __shared__ float lx[NC], ly[NC], lz[NC];
    __shared__ short lcell[NC];
    const int t = threadIdx.x;
    if (blockIdx.x >= NB) {
        int e = (blockIdx.x - NB)*256 + t;
        if (e < CMID*CIN) {
            int n = e / CIN, k = e % CIN;
            W1at[e] = __float2bfloat16(W1[(size_t)k*CMID + n]);
        }
        int e2 = e - CMID*CIN;
        if (e2 >= 0 && e2 < 2*2048*8) {          // imgG (W1b rows, K=128)
            int chunk = e2 >> 3, el = e2 & 7;
            int s = chunk >> 11, L = chunk & 2047;
            int rr = L >> 3, sl = L & 7;
            int k = s*64 + ((sl ^ (rr & 7)) << 3) + el;
            imgG[e2] = __float2bfloat16(W1[(size_t)(CIN + k)*CMID + rr]);
        }
        int e3 = e2 - 2*2048*8;
        if (e3 >= 0 && e3 < 4*2048*8) {          // img2 (W2 rows, K=256)
            int chunk = e3 >> 3, el = e3 & 7;
            int s = chunk >> 11, L = chunk & 2047;
            int rr = L >> 3, sl = L & 7;
            int k = s*64 + ((sl ^ (rr & 7)) << 3) + el;
            img2[e3] = __float2bfloat16(W2[(size_t)k*COUT + rr]);
        }
        return;
    }
    const int b = blockIdx.x;
    for (int i = t; i < 512; i += 256) cnt[i] = 0;
    __syncthreads();
    const float* pc = pos + (size_t)b*NC*3;
    #pragma unroll
    for (int u = 0; u < 4; ++u) {
        int i = t + u*256;
        float x = pc[3*i+0], y = pc[3*i+1], z = pc[3*i+2];
        int cx = min(7, (int)(x*8.0f));
        int cy = min(7, (int)(y*8.0f));
        int cz = min(7, (int)(z*8.0f));
        int c = (cz*8 + cy)*8 + cx;
        lx[i] = x; ly[i] = y; lz[i] = z; lcell[i] = (short)c;
        atomicAdd(&cnt[c], 1);
    }
    __syncthreads();
    if (t < 64) {
        int v[8]; int s = 0;
        #pragma unroll
        for (int u = 0; u < 8; ++u) { v[u] = cnt[t*8+u]; s += v[u]; }
        int pfx = s;
        #pragma unroll
        for (int m = 1; m < 64; m <<= 1) {
            int o = __shfl_up(pfx, m);
            if (t >= m) pfx += o;
        }
        pfx -= s;
        #pragma unroll
        for (int u = 0; u < 8; ++u) {
            gcs[b*513 + t*8+u] = pfx;
            cnt[t*8+u] = pfx;
            pfx += v[u];
        }
        if (t == 63) gcs[b*513 + 512] = NC;
    }
    __syncthreads();
    #pragma unroll
    for (int u = 0; u < 4; ++u) {
        int i = t + u*256;
        int c = lcell[i];
        int dst = atomicAdd(&cnt[c], 1);
        f32x4 v; v[0] = lx[i]; v[1] = ly[i]; v[2] = lz[i]; v[3] = __int_as_float(i);
        *(f32x4*)&gp[(size_t)(b*NC + dst)*4] = v;
    }
}

// ---------------- K1: knn (blocks 0..511, 4 lanes/query) + gemmZ (blocks 512..767) ----------------
#define KQPB 128

#define INS(d, j) do {                                        \
    bool c2 = (d) < dB, c1 = (d) < dA, c0 = (d) < d0;         \
    dB = c1 ? dA : (c2 ? (d) : dB);                           \
    iB = c1 ? iA : (c2 ? (j) : iB);                           \
    dA = c0 ? d0 : (c1 ? (d) : dA);                           \
    iA = c0 ? i0 : (c1 ? (j) : iA);                           \
    d0 = c0 ? (d) : d0;                                       \
    i0 = c0 ? (j) : i0;                                       \
} while (0)

#define SCAN(JS, JE) for (int j = (JS) + g; j < (JE); j += 4) {        \
    const f32x4 p = *(const f32x4*)&pp[j][0];                          \
    float fx = qx - p[0], fy = qy - p[1], fz = qz - p[2];              \
    float dd = fx*fx + fy*fy + fz*fz;                                  \
    INS(dd, j);                                                        \
}

#define MERGE4() do {                                                          \
    _Pragma("unroll")                                                          \
    for (int mm = 1; mm < 4; mm <<= 1) {                                       \
        float e0 = __shfl_xor(d0, mm), e1 = __shfl_xor(dA, mm), e2 = __shfl_xor(dB, mm); \
        int   f0 = __shfl_xor(i0, mm), f1 = __shfl_xor(iA, mm), f2 = __shfl_xor(iB, mm); \
        INS(e0, f0); INS(e1, f1); INS(e2, f2);                                 \
    }                                                                          \
} while (0)

union KZMem {
    struct { float pp[NC][4]; unsigned short cs[513]; } k;
    struct { short As[64][64]; short Bs[256][64]; } z;
};

__global__ __launch_bounds__(512, 2)
void knnZ_kernel(const float* __restrict__ pos_skip,
                 const float* __restrict__ gp,
                 const int* __restrict__ gcs,
                 int* __restrict__ widx, float* __restrict__ wval,
                 float* __restrict__ out,
                 const float* __restrict__ x,
                 const __hip_bfloat16* __restrict__ W1at,
                 __hip_bfloat16* __restrict__ Z)
{
    __shared__ __align__(16) KZMem sm;
    const int t = threadIdx.x;

    if (blockIdx.x >= 512) {
        // ================= gemmZ: Z = x @ W1a =================
        const int m0 = (blockIdx.x - 512) * 64;
        const int wave = t >> 6, lane = t & 63;
        const int wm = wave >> 2, wn = wave & 3;
        const int rl = lane & 15, kq = lane >> 4;
        const short* Br = (const short*)W1at;
        const int ar = t >> 3;
        const int ac = t & 7;
        f32x4 rA[2];
        u32x4 rB[4];

        #define LOADAZ(K0) do {                                                \
            const float* p = &x[(size_t)(m0+ar)*CIN + (K0) + ac*8];            \
            rA[0] = *(const f32x4*)p; rA[1] = *(const f32x4*)(p+4);            \
        } while (0)
        #define LOADBZ(K0) do {                                                \
            _Pragma("unroll")                                                  \
            for (int i = 0; i < 4; ++i) {                                      \
                const int ch = t + i*512;                                      \
                const int rr = ch >> 3, cc = ch & 7;                           \
                rB[i] = *(const u32x4*)&Br[(size_t)rr*CIN + (K0) + cc*8];      \
            }                                                                  \
        } while (0)

        f32x4 acc[2][4] = {};
        LOADAZ(0); LOADBZ(0);
        #pragma unroll
        for (int s = 0; s < 4; ++s) {
            __syncthreads();
            {
                short8 sv;
                #pragma unroll
                for (int u = 0; u < 2; ++u) {
                    f32x4 a = rA[u];
                    #pragma unroll
                    for (int e = 0; e < 4; ++e) {
                        __hip_bfloat16 bb = __float2bfloat16(a[e]);
                        ((short*)&sv)[u*4+e] = *(short*)&bb;
                    }
                }
                *(short8*)&sm.z.As[ar][(ac ^ (ar&7))*8] = sv;
            }
            #pragma unroll
            for (int i = 0; i < 4; ++i) {
                const int ch = t + i*512;
                const int rr = ch >> 3, cc = ch & 7;
                *(u32x4*)&sm.z.Bs[rr][(cc ^ (rr&7))*8] = rB[i];
            }
            __syncthreads();
            if (s < 3) { LOADAZ((s+1)*64); LOADBZ((s+1)*64); }
            #pragma unroll
            for (int kh = 0; kh < 2; ++kh) {
                const int kc = kh*4 + kq;
                short8 af[2], bf[4];
                #pragma unroll
                for (int mf = 0; mf < 2; ++mf)
                    af[mf] = *(const short8*)&sm.z.As[wm*32 + mf*16 + rl][(kc ^ (rl&7))*8];
                #pragma unroll
                for (int nf = 0; nf < 4; ++nf)
                    bf[nf] = *(const short8*)&sm.z.Bs[wn*64 + nf*16 + rl][(kc ^ (rl&7))*8];
                #pragma unroll
                for (int mf = 0; mf < 2; ++mf)
                #pragma unroll
                for (int nf = 0; nf < 4; ++nf)
                    acc[mf][nf] = __builtin_amdgcn_mfma_f32_16x16x32_bf16(af[mf], bf[nf], acc[mf][nf], 0,0,0);
            }
        }
        #undef LOADAZ
        #undef LOADBZ
        #pragma unroll
        for (int mf = 0; mf < 2; ++mf)
        #pragma unroll
        for (int nf = 0; nf < 4; ++nf) {
            const int col = wn*64 + nf*16 + rl;
            #pragma unroll
            for (int i = 0; i < 4; ++i) {
                const int row = m0 + wm*32 + mf*16 + kq*4 + i;
                Z[(size_t)row*CMID + col] = __float2bfloat16(acc[mf][nf][i]);
            }
        }
        return;
    }

    // ================= knn, 4 lanes/query (+ fused tail writes) =================
    float (*pp)[4] = sm.k.pp;
    unsigned short* cs = sm.k.cs;
    const int bpc = NF/KQPB;              // 32 blocks per cloud
    const int b  = blockIdx.x / bpc;
    const int qb = blockIdx.x % bpc;

    {
        if (t < 384) out[(size_t)NFINE*COUT + blockIdx.x*384 + t] = pos_skip[blockIdx.x*384 + t];
        if (t >= 384) {
            int e2 = blockIdx.x*128 + (t - 384);
            out[(size_t)NFINE*COUT + (size_t)NFINE*3 + e2] = (float)(e2 >> 12);  // /NF
        }
    }

    for (int i = t; i < NC; i += 512)
        *(f32x4*)&pp[i][0] = *(const f32x4*)&gp[(size_t)(b*NC + i)*4];
    for (int i = t; i < 513; i += 512) cs[i] = (unsigned short)gcs[b*513 + i];
    __syncthreads();

    const int g  = t & 3;
    const int ql = t >> 2;                // 0..127
    const int q  = b*NF + qb*KQPB + ql;
    const float qx = pos_skip[(size_t)q*3+0];
    const float qy = pos_skip[(size_t)q*3+1];
    const float qz = pos_skip[(size_t)q*3+2];
    const int cx = min(7, (int)(qx*8.0f));
    const int cy = min(7, (int)(qy*8.0f));
    const int cz = min(7, (int)(qz*8.0f));

    float d0 = 3.0e38f, dA = 3.0e38f, dB = 3.0e38f;
    int   i0 = 0,       iA = 0,       iB = 0;

    const int xlo = max(cx-1,0), xhi = min(cx+1,7);
    const int ylo = max(cy-1,0), yhi = min(cy+1,7);
    const int zlo = max(cz-1,0), zhi = min(cz+1,7);
    #pragma unroll
    for (int r = 0; r < 9; ++r) {
        const int z = cz - 1 + r/3;
        const int y = cy - 1 + r%3;
        const bool ok = ((unsigned)z < 8u) & ((unsigned)y < 8u);
        const int rb = (z*8 + y)*8;
        int js = 0, je = 0;
        if (ok) { js = cs[rb + xlo]; je = cs[rb + xhi + 1]; }
        SCAN(js, je);
    }
    MERGE4();

    float m1 = 3.0e38f;
    if (xlo > 0) m1 = fminf(m1, qx - xlo*0.125f);
    if (xhi < 7) m1 = fminf(m1, (xhi+1)*0.125f - qx);
    if (ylo > 0) m1 = fminf(m1, qy - ylo*0.125f);
    if (yhi < 7) m1 = fminf(m1, (yhi+1)*0.125f - qy);
    if (zlo > 0) m1 = fminf(m1, qz - zlo*0.125f);
    if (zhi < 7) m1 = fminf(m1, (zhi+1)*0.125f - qz);

    if (dB > m1*m1) {
        const float s0 = d0, s1 = dA, s2 = dB;
        const int   t0 = i0, t1 = iA, t2 = iB;
        d0 = dA = dB = 3.0e38f; i0 = iA = iB = 0;
        const int xlo2 = max(cx-2,0), xhi2 = min(cx+2,7);
        const int ylo2 = max(cy-2,0), yhi2 = min(cy+2,7);
        const int zlo2 = max(cz-2,0), zhi2 = min(cz+2,7);
        for (int z = zlo2; z <= zhi2; ++z)
        for (int y = ylo2; y <= yhi2; ++y) {
            const int rb = (z*8 + y)*8;
            const bool inner_zy = (z >= zlo && z <= zhi && y >= ylo && y <= yhi);
            int jsA, jeA, jsB, jeB;
            if (inner_zy) {
                jsA = cs[rb + xlo2]; jeA = cs[rb + xlo];
                jsB = cs[rb + xhi + 1]; jeB = cs[rb + xhi2 + 1];
            } else {
                jsA = cs[rb + xlo2]; jeA = cs[rb + xhi2 + 1];
                jsB = 0; jeB = 0;
            }
            SCAN(jsA, jeA);
            SCAN(jsB, jeB);
        }
        MERGE4();
        INS(s0, t0); INS(s1, t1); INS(s2, t2);

        float m2 = 3.0e38f;
        if (xlo2 > 0) m2 = fminf(m2, qx - xlo2*0.125f);
        if (xhi2 < 7) m2 = fminf(m2, (xhi2+1)*0.125f - qx);
        if (ylo2 > 0) m2 = fminf(m2, qy - ylo2*0.125f);
        if (yhi2 < 7) m2 = fminf(m2, (yhi2+1)*0.125f - qy);
        if (zlo2 > 0) m2 = fminf(m2, qz - zlo2*0.125f);
        if (zhi2 < 7) m2 = fminf(m2, (zhi2+1)*0.125f - qz);
        if (dB > m2*m2) {
            const float u0 = d0, u1 = dA, u2 = dB;
            const int   v0 = i0, v1 = iA, v2 = iB;
            d0 = dA = dB = 3.0e38f; i0 = iA = iB = 0;
            for (int j = g; j < NC; j += 4) {
                const f32x4 p = *(const f32x4*)&pp[j][0];
                int pcx = min(7, (int)(p[0]*8.0f));
                int pcy = min(7, (int)(p[1]*8.0f));
                int pcz = min(7, (int)(p[2]*8.0f));
                if (pcx >= xlo2 && pcx <= xhi2 && pcy >= ylo2 && pcy <= yhi2 &&
                    pcz >= zlo2 && pcz <= zhi2) continue;
                float fx = qx - p[0], fy = qy - p[1], fz = qz - p[2];
                float dd = fx*fx + fy*fy + fz*fz;
                INS(dd, j);
            }
            MERGE4();
            INS(u0, v0); INS(u1, v1); INS(u2, v2);
        }
    }

    if (g == 0) {
        const int o0 = __float_as_int(pp[i0][3]);
        const int o1 = __float_as_int(pp[iA][3]);
        const int o2 = __float_as_int(pp[iB][3]);
        float w0 = 1.0f / fmaxf(d0, 1e-16f);
        float w1 = 1.0f / fmaxf(dA, 1e-16f);
        float w2 = 1.0f / fmaxf(dB, 1e-16f);
        float inv = 1.0f / (w0 + w1 + w2);
        widx[q*3+0] = b*NC + o0;  wval[q*3+0] = w0*inv;
        widx[q*3+1] = b*NC + o1;  wval[q*3+1] = w1*inv;
        widx[q*3+2] = b*NC + o2;  wval[q*3+2] = w2*inv;
    }
}

// ---------------- g2_fused persistent: 2 consecutive m-tiles per block, grid 512 ----------------
// r14 structure per tile; imgG regs (rG0/rG1) loaded ONCE (tile-independent);
// tile-B x_skip prologue issued during tile A (latency fully hidden).
__global__ __launch_bounds__(512, 2)
void g2_fused(const float* __restrict__ x_skip,
              const float* __restrict__ b1,
              const __hip_bfloat16* __restrict__ Z,      // [NB*NC][CMID]
              const int* __restrict__ widx,
              const float* __restrict__ wval,
              const __hip_bfloat16* __restrict__ imgG,   // 2 step-images
              const __hip_bfloat16* __restrict__ img2,   // 4 step-images
              const float* __restrict__ b2,
              float* __restrict__ out)
{
    __shared__ __align__(16) short As[64][128];    // 16KB
    __shared__ __align__(16) short Bs[256][64];    // 32KB
    __shared__ __align__(16) short Hs[64][256];    // 32KB
    const int nwg = gridDim.x;                     // 512 (%8==0)
    const int pair = (blockIdx.x & 7)*(nwg >> 3) + (blockIdx.x >> 3);

    const int t = threadIdx.x;
    const int wave = t >> 6, lane = t & 63;
    const int wm = wave >> 2, wn = wave & 3;
    const int rl = lane & 15, kq = lane >> 4;
    const short* gI = (const short*)imgG;
    const short* g2i = (const short*)img2;
    const short* Zr  = (const short*)Z;
    short* BsLin = &Bs[0][0];
    short (*BsH)[64] = (short(*)[64])&Hs[0][0];

    const int ar = t >> 3;        // 0..63
    const int ac = t & 7;
    const int sw = ac ^ (ar & 7);

    // tile-independent phase-G B images: load ONCE, kept live across both tiles
    u32x4 rG0[4], rG1[4];
    #pragma unroll
    for (int i = 0; i < 4; ++i) {
        rG0[i] = *(const u32x4*)&gI[(size_t)(       i*512 + t)*8];
        rG1[i] = *(const u32x4*)&gI[(size_t)(2048 + i*512 + t)*8];
    }

    int m0 = pair * 128;
    // A prologue for tile 0
    f32x4 pa0, pa1, pb0, pb1;
    {
        const float* xs = &x_skip[(size_t)(m0+ar)*CSKIP];
        pa0 = *(const f32x4*)&xs[ac*8];
        pa1 = *(const f32x4*)&xs[ac*8+4];
        pb0 = *(const f32x4*)&xs[64+ac*8];
        pb1 = *(const f32x4*)&xs[64+ac*8+4];
    }

    for (int half = 0; half < 2; ++half) {
        // ---- stage As (cvt) + Bs/BsH (linear from regs) ----
        {
            short8 sv0, sv1;
            #pragma unroll
            for (int u = 0; u < 2; ++u) {
                f32x4 a = (u == 0) ? pa0 : pa1;
                f32x4 b = (u == 0) ? pb0 : pb1;
                #pragma unroll
                for (int e = 0; e < 4; ++e) {
                    __hip_bfloat16 ba = __float2bfloat16(a[e]);
                    __hip_bfloat16 bb = __float2bfloat16(b[e]);
                    ((short*)&sv0)[u*4+e] = *(short*)&ba;
                    ((short*)&sv1)[u*4+e] = *(short*)&bb;
                }
            }
            *(short8*)&As[ar][sw*8]     = sv0;
            *(short8*)&As[ar][(8+sw)*8] = sv1;
        }
        #pragma unroll
        for (int i = 0; i < 4; ++i) {
            *(u32x4*)&BsLin[(size_t)(i*512 + t)*8]       = rG0[i];
            *(u32x4*)&(&Hs[0][0])[(size_t)(i*512 + t)*8] = rG1[i];
        }
        // ---- preload tile-1 A panel NOW (hidden under this tile's whole chain) ----
        if (half == 0) {
            const float* xs2 = &x_skip[(size_t)(m0+64+ar)*CSKIP];
            pa0 = *(const f32x4*)&xs2[ac*8];
            pa1 = *(const f32x4*)&xs2[ac*8+4];
            pb0 = *(const f32x4*)&xs2[64+ac*8];
            pb1 = *(const f32x4*)&xs2[64+ac*8+4];
        }
        __syncthreads();   // [B1]

        f32x4 acc[2][4] = {};
        #pragma unroll
        for (int kh = 0; kh < 2; ++kh) {        // step 0 (Bs)
            const int kc = kh*4 + kq;
            short8 af[2], bf[4];
            #pragma unroll
            for (int mf = 0; mf < 2; ++mf)
                af[mf] = *(const short8*)&As[wm*32 + mf*16 + rl][((kc ^ (rl&7)))*8];
            #pragma unroll
            for (int nf = 0; nf < 4; ++nf)
                bf[nf] = *(const short8*)&Bs[wn*64 + nf*16 + rl][(kc ^ (rl&7))*8];
            #pragma unroll
            for (int mf = 0; mf < 2; ++mf)
            #pragma unroll
            for (int nf = 0; nf < 4; ++nf)
                acc[mf][nf] = __builtin_amdgcn_mfma_f32_16x16x32_bf16(af[mf], bf[nf], acc[mf][nf], 0,0,0);
        }
        #pragma unroll
        for (int kh = 0; kh < 2; ++kh) {        // step 1 (Hs region)
            const int kc = kh*4 + kq;
            short8 af[2], bf[4];
            #pragma unroll
            for (int mf = 0; mf < 2; ++mf)
                af[mf] = *(const short8*)&As[wm*32 + mf*16 + rl][(8 + (kc ^ (rl&7)))*8];
            #pragma unroll
            for (int nf = 0; nf < 4; ++nf)
                bf[nf] = *(const short8*)&BsH[wn*64 + nf*16 + rl][(kc ^ (rl&7))*8];
            #pragma unroll
            for (int mf = 0; mf < 2; ++mf)
            #pragma unroll
            for (int nf = 0; nf < 4; ++nf)
                acc[mf][nf] = __builtin_amdgcn_mfma_f32_16x16x32_bf16(af[mf], bf[nf], acc[mf][nf], 0,0,0);
        }
        __syncthreads();   // [B2]

        u32x4 rB[4];
        #pragma unroll
        for (int i = 0; i < 4; ++i)
            rB[i] = *(const u32x4*)&g2i[(size_t)(i*512 + t)*8];
        #pragma unroll
        for (int mf = 0; mf < 2; ++mf)
        #pragma unroll
        for (int nf = 0; nf < 4; ++nf) {
            const int col = wn*64 + nf*16 + rl;
            const float bv = b1[col];
            #pragma unroll
            for (int i = 0; i < 4; ++i) {
                const int row = wm*32 + mf*16 + kq*4 + i;
                float v = acc[mf][nf][i] + bv;
                __hip_bfloat16 bb = __float2bfloat16(v);
                Hs[row][((col >> 3) ^ (row & 7))*8 + (col & 7)] = *(short*)&bb;
            }
        }
        #pragma unroll
        for (int i = 0; i < 4; ++i)
            *(u32x4*)&BsLin[(size_t)(i*512 + t)*8] = rB[i];
        __syncthreads();   // [B3]

        #pragma unroll
        for (int u = 0; u < 4; ++u) {
            const int ch = t + u*512;
            const int row = ch >> 5;
            const int cc  = ch & 31;
            const int c   = cc * 8;
            const int gr = (m0 + row)*3;
            const int j0 = widx[gr+0], j1 = widx[gr+1], j2 = widx[gr+2];
            const float w0 = wval[gr+0], w1 = wval[gr+1], w2 = wval[gr+2];
            const short8 z0 = *(const short8*)&Zr[(size_t)j0*CMID + c];
            const short8 z1 = *(const short8*)&Zr[(size_t)j1*CMID + c];
            const short8 z2 = *(const short8*)&Zr[(size_t)j2*CMID + c];
            const int slot = (cc ^ (row & 7))*8;
            short8 gchunk = *(const short8*)&Hs[row][slot];
            short8 r;
            #pragma unroll
            for (int e = 0; e < 8; ++e) {
                float v = bf2f(gchunk[e]) + w0*bf2f(z0[e]) + w1*bf2f(z1[e]) + w2*bf2f(z2[e]);
                v = fmaxf(v, 0.0f);
                __hip_bfloat16 bb = __float2bfloat16(v);
                r[e] = *(short*)&bb;
            }
            *(short8*)&Hs[row][slot] = r;
        }
        __syncthreads();   // [B4]

        f32x4 acc2[2][4] = {};
        #define MFMA2(S2) do {                                                     \
            _Pragma("unroll")                                                      \
            for (int kh = 0; kh < 2; ++kh) {                                       \
                const int kcl = kh*4 + kq;                                         \
                const int kca = (S2)*8 + kcl;                                      \
                short8 af[2], bf[4];                                               \
                _Pragma("unroll")                                                  \
                for (int mf = 0; mf < 2; ++mf)                                     \
                    af[mf] = *(const short8*)&Hs[wm*32 + mf*16 + rl][(kca ^ (rl&7))*8]; \
                _Pragma("unroll")                                                  \
                for (int nf = 0; nf < 4; ++nf)                                     \
                    bf[nf] = *(const short8*)&Bs[wn*64 + nf*16 + rl][(kcl ^ (rl&7))*8]; \
                _Pragma("unroll")                                                  \
                for (int mf = 0; mf < 2; ++mf)                                     \
                _Pragma("unroll")                                                  \
                for (int nf = 0; nf < 4; ++nf)                                     \
                    acc2[mf][nf] = __builtin_amdgcn_mfma_f32_16x16x32_bf16(af[mf], bf[nf], acc2[mf][nf], 0,0,0); \
            }                                                                      \
        } while (0)
        #define LOADI2(S) do {                                                     \
            _Pragma("unroll")                                                      \
            for (int i = 0; i < 4; ++i)                                            \
                rB[i] = *(const u32x4*)&g2i[(size_t)((S)*2048 + i*512 + t)*8];     \
        } while (0)
        #define STAGEI2() do {                                                     \
            _Pragma("unroll")                                                      \
            for (int i = 0; i < 4; ++i)                                            \
                *(u32x4*)&BsLin[(size_t)(i*512 + t)*8] = rB[i];                    \
        } while (0)

        LOADI2(1);
        MFMA2(0);
        __syncthreads();   // [B5]
        STAGEI2();
        __syncthreads();   // [B6]
        LOADI2(2);
        MFMA2(1);
        __syncthreads();   // [B7]
        STAGEI2();
        __syncthreads();   // [B8]
        LOADI2(3);
        MFMA2(2);
        __syncthreads();   // [B9]
        STAGEI2();
        __syncthreads();   // [B10]
        MFMA2(3);
        #undef MFMA2
        #undef LOADI2
        #undef STAGEI2

        // ---- epilogue 2: relu+bias -> out f32 (nontemporal: write-once buffer) ----
        #pragma unroll
        for (int mf = 0; mf < 2; ++mf)
        #pragma unroll
        for (int nf = 0; nf < 4; ++nf) {
            const int col = wn*64 + nf*16 + rl;
            const float bv = b2[col];
            #pragma unroll
            for (int i = 0; i < 4; ++i) {
                const int row = m0 + wm*32 + mf*16 + kq*4 + i;
                __builtin_nontemporal_store(fmaxf(acc2[mf][nf][i] + bv, 0.0f),
                                            &out[(size_t)row*COUT + col]);
            }
        }

        if (half == 0) {
            m0 += 64;
            __syncthreads();   // [B11] all tile-0 LDS reads done -> safe to restage
        }
    }
}

extern "C" void kernel_launch(void* const* d_in, const int* in_sizes, int n_in,
                              void* d_out, int out_size, void* d_ws, size_t ws_size,
                              hipStream_t stream) {
    const float* x        = (const float*)d_in[0];
    const float* pos      = (const float*)d_in[1];
    const float* x_skip   = (const float*)d_in[4];
    const float* pos_skip = (const float*)d_in[5];
    const float* W1       = (const float*)d_in[8];
    const float* b1       = (const float*)d_in[9];
    const float* W2       = (const float*)d_in[10];
    const float* b2       = (const float*)d_in[11];
    float* out = (float*)d_out;
    char* ws = (char*)d_ws;

    int*            widx = (int*)  (ws + 0);                  //   786,432 B
    float*          wval = (float*)(ws + 786432);             //   786,432 B
    __hip_bfloat16* W1at = (__hip_bfloat16*)(ws + 1572864);   //   131,072 B
    __hip_bfloat16* imgG = (__hip_bfloat16*)(ws + 1703936);   //    65,536 B
    __hip_bfloat16* img2 = (__hip_bfloat16*)(ws + 1769472);   //   131,072 B
    float*          gp   = (float*)(ws + 1900544);            //   262,144 B
    int*            gcs  = (int*)  (ws + 2162688);            //    32,832 B (pad)
    __hip_bfloat16* Z    = (__hip_bfloat16*)(ws + 2195520);   // 8,388,608 B -> 10,584,128 total

    // launch 1: bin (16 blocks) + prep (640 blocks)
    hipLaunchKernelGGL(binprep_kernel, dim3(NB + 640), dim3(256), 0, stream,
                       pos, gp, gcs, W1, W2, W1at, imgG, img2);
    // launch 2: knn (512 blocks, 4 lanes/query) + gemmZ (256 blocks)
    hipLaunchKernelGGL(knnZ_kernel, dim3(512 + 256), dim3(512), 0, stream,
                       pos_skip, gp, gcs, widx, wval, out, x, W1at, Z);
    // launch 3: fused MLP, persistent 2-tile blocks (512 blocks, 1 grid round)
    hipLaunchKernelGGL(g2_fused, dim3(NFINE/128), dim3(512), 0, stream,
                       x_skip, b1, Z, widx, wval, imgG, img2, b2, out);
}

// Round 21
// 63.749 us; speedup vs baseline: 1.1284x; 1.1284x over previous
//
#include <hip/hip_runtime.h>
#include <hip/hip_bf16.h>

// Problem constants (fixed by setup_inputs)
#define NB    16
#define NC    1024
#define NF    4096
#define NFINE (NB*NF)     // 65536
#define CIN   256
#define CSKIP 128
#define KH    (CIN+CSKIP) // 384
#define CMID  256
#define COUT  256

typedef __attribute__((ext_vector_type(8))) short short8;
typedef __attribute__((ext_vector_type(4))) float f32x4;
typedef __attribute__((ext_vector_type(4))) unsigned int u32x4;

__device__ __forceinline__ float bf2f(short s) {
    return __uint_as_float(((unsigned)(unsigned short)s) << 16);
}

// ---------------- K0: bin (blocks 0..15) + prep (blocks 16..655) ----------------
__global__ __launch_bounds__(256)
void binprep_kernel(const float* __restrict__ pos,
                    float* __restrict__ gp, int* __restrict__ gcs,
                    const float* __restrict__ W1, const float* __restrict__ W2,
                    __hip_bfloat16* __restrict__ W1at,
                    __hip_bfloat16* __restrict__ imgG,
                    __hip_bfloat16* __restrict__ img2)
{
    __shared__ int cnt[512];
    __shared__ float lx[NC], ly[NC], lz[NC];
    __shared__ short lcell[NC];
    const int t = threadIdx.x;
    if (blockIdx.x >= NB) {
        int e = (blockIdx.x - NB)*256 + t;
        if (e < CMID*CIN) {
            int n = e / CIN, k = e % CIN;
            W1at[e] = __float2bfloat16(W1[(size_t)k*CMID + n]);
        }
        int e2 = e - CMID*CIN;
        if (e2 >= 0 && e2 < 2*2048*8) {          // imgG (W1b rows, K=128)
            int chunk = e2 >> 3, el = e2 & 7;
            int s = chunk >> 11, L = chunk & 2047;
            int rr = L >> 3, sl = L & 7;
            int k = s*64 + ((sl ^ (rr & 7)) << 3) + el;
            imgG[e2] = __float2bfloat16(W1[(size_t)(CIN + k)*CMID + rr]);
        }
        int e3 = e2 - 2*2048*8;
        if (e3 >= 0 && e3 < 4*2048*8) {          // img2 (W2 rows, K=256)
            int chunk = e3 >> 3, el = e3 & 7;
            int s = chunk >> 11, L = chunk & 2047;
            int rr = L >> 3, sl = L & 7;
            int k = s*64 + ((sl ^ (rr & 7)) << 3) + el;
            img2[e3] = __float2bfloat16(W2[(size_t)k*COUT + rr]);
        }
        return;
    }
    const int b = blockIdx.x;
    for (int i = t; i < 512; i += 256) cnt[i] = 0;
    __syncthreads();
    const float* pc = pos + (size_t)b*NC*3;
    #pragma unroll
    for (int u = 0; u < 4; ++u) {
        int i = t + u*256;
        float x = pc[3*i+0], y = pc[3*i+1], z = pc[3*i+2];
        int cx = min(7, (int)(x*8.0f));
        int cy = min(7, (int)(y*8.0f));
        int cz = min(7, (int)(z*8.0f));
        int c = (cz*8 + cy)*8 + cx;
        lx[i] = x; ly[i] = y; lz[i] = z; lcell[i] = (short)c;
        atomicAdd(&cnt[c], 1);
    }
    __syncthreads();
    if (t < 64) {
        int v[8]; int s = 0;
        #pragma unroll
        for (int u = 0; u < 8; ++u) { v[u] = cnt[t*8+u]; s += v[u]; }
        int pfx = s;
        #pragma unroll
        for (int m = 1; m < 64; m <<= 1) {
            int o = __shfl_up(pfx, m);
            if (t >= m) pfx += o;
        }
        pfx -= s;
        #pragma unroll
        for (int u = 0; u < 8; ++u) {
            gcs[b*513 + t*8+u] = pfx;
            cnt[t*8+u] = pfx;
            pfx += v[u];
        }
        if (t == 63) gcs[b*513 + 512] = NC;
    }
    __syncthreads();
    #pragma unroll
    for (int u = 0; u < 4; ++u) {
        int i = t + u*256;
        int c = lcell[i];
        int dst = atomicAdd(&cnt[c], 1);
        f32x4 v; v[0] = lx[i]; v[1] = ly[i]; v[2] = lz[i]; v[3] = __int_as_float(i);
        *(f32x4*)&gp[(size_t)(b*NC + dst)*4] = v;
    }
}

// ---------------- K1: knn (blocks 0..1023) + gemmZ (blocks 1024..1279) ----------------
#define KQPB 64

#define INS(d, j) do {                                        \
    bool c2 = (d) < dB, c1 = (d) < dA, c0 = (d) < d0;         \
    dB = c1 ? dA : (c2 ? (d) : dB);                           \
    iB = c1 ? iA : (c2 ? (j) : iB);                           \
    dA = c0 ? d0 : (c1 ? (d) : dA);                           \
    iA = c0 ? i0 : (c1 ? (j) : iA);                           \
    d0 = c0 ? (d) : d0;                                       \
    i0 = c0 ? (j) : i0;                                       \
} while (0)

#define SCAN(JS, JE) for (int j = (JS) + g; j < (JE); j += 8) {        \
    const f32x4 p = *(const f32x4*)&pp[j][0];                          \
    float fx = qx - p[0], fy = qy - p[1], fz = qz - p[2];              \
    float dd = fx*fx + fy*fy + fz*fz;                                  \
    INS(dd, j);                                                        \
}

#define MERGE8() do {                                                          \
    _Pragma("unroll")                                                          \
    for (int mm = 1; mm < 8; mm <<= 1) {                                       \
        float e0 = __shfl_xor(d0, mm), e1 = __shfl_xor(dA, mm), e2 = __shfl_xor(dB, mm); \
        int   f0 = __shfl_xor(i0, mm), f1 = __shfl_xor(iA, mm), f2 = __shfl_xor(iB, mm); \
        INS(e0, f0); INS(e1, f1); INS(e2, f2);                                 \
    }                                                                          \
} while (0)

union KZMem {
    struct { float pp[NC][4]; unsigned short cs[513]; } k;
    struct { short As[64][64]; short Bs[256][64]; } z;
};

__global__ __launch_bounds__(512, 2)
void knnZ_kernel(const float* __restrict__ pos_skip,
                 const float* __restrict__ gp,
                 const int* __restrict__ gcs,
                 int* __restrict__ widx, float* __restrict__ wval,
                 float* __restrict__ out,
                 const float* __restrict__ x,
                 const __hip_bfloat16* __restrict__ W1at,
                 __hip_bfloat16* __restrict__ Z)
{
    __shared__ __align__(16) KZMem sm;
    const int t = threadIdx.x;

    if (blockIdx.x >= 1024) {
        // ================= gemmZ: Z = x @ W1a =================
        const int m0 = (blockIdx.x - 1024) * 64;
        const int wave = t >> 6, lane = t & 63;
        const int wm = wave >> 2, wn = wave & 3;
        const int rl = lane & 15, kq = lane >> 4;
        const short* Br = (const short*)W1at;
        const int ar = t >> 3;
        const int ac = t & 7;
        f32x4 rA[2];
        u32x4 rB[4];

        #define LOADAZ(K0) do {                                                \
            const float* p = &x[(size_t)(m0+ar)*CIN + (K0) + ac*8];            \
            rA[0] = *(const f32x4*)p; rA[1] = *(const f32x4*)(p+4);            \
        } while (0)
        #define LOADBZ(K0) do {                                                \
            _Pragma("unroll")                                                  \
            for (int i = 0; i < 4; ++i) {                                      \
                const int ch = t + i*512;                                      \
                const int rr = ch >> 3, cc = ch & 7;                           \
                rB[i] = *(const u32x4*)&Br[(size_t)rr*CIN + (K0) + cc*8];      \
            }                                                                  \
        } while (0)

        f32x4 acc[2][4] = {};
        LOADAZ(0); LOADBZ(0);
        #pragma unroll
        for (int s = 0; s < 4; ++s) {
            __syncthreads();
            {
                short8 sv;
                #pragma unroll
                for (int u = 0; u < 2; ++u) {
                    f32x4 a = rA[u];
                    #pragma unroll
                    for (int e = 0; e < 4; ++e) {
                        __hip_bfloat16 bb = __float2bfloat16(a[e]);
                        ((short*)&sv)[u*4+e] = *(short*)&bb;
                    }
                }
                *(short8*)&sm.z.As[ar][(ac ^ (ar&7))*8] = sv;
            }
            #pragma unroll
            for (int i = 0; i < 4; ++i) {
                const int ch = t + i*512;
                const int rr = ch >> 3, cc = ch & 7;
                *(u32x4*)&sm.z.Bs[rr][(cc ^ (rr&7))*8] = rB[i];
            }
            __syncthreads();
            if (s < 3) { LOADAZ((s+1)*64); LOADBZ((s+1)*64); }
            #pragma unroll
            for (int kh = 0; kh < 2; ++kh) {
                const int kc = kh*4 + kq;
                short8 af[2], bf[4];
                #pragma unroll
                for (int mf = 0; mf < 2; ++mf)
                    af[mf] = *(const short8*)&sm.z.As[wm*32 + mf*16 + rl][(kc ^ (rl&7))*8];
                #pragma unroll
                for (int nf = 0; nf < 4; ++nf)
                    bf[nf] = *(const short8*)&sm.z.Bs[wn*64 + nf*16 + rl][(kc ^ (rl&7))*8];
                #pragma unroll
                for (int mf = 0; mf < 2; ++mf)
                #pragma unroll
                for (int nf = 0; nf < 4; ++nf)
                    acc[mf][nf] = __builtin_amdgcn_mfma_f32_16x16x32_bf16(af[mf], bf[nf], acc[mf][nf], 0,0,0);
            }
        }
        #undef LOADAZ
        #undef LOADBZ
        #pragma unroll
        for (int mf = 0; mf < 2; ++mf)
        #pragma unroll
        for (int nf = 0; nf < 4; ++nf) {
            const int col = wn*64 + nf*16 + rl;
            #pragma unroll
            for (int i = 0; i < 4; ++i) {
                const int row = m0 + wm*32 + mf*16 + kq*4 + i;
                Z[(size_t)row*CMID + col] = __float2bfloat16(acc[mf][nf][i]);
            }
        }
        return;
    }

    // ================= knn (+ fused tail writes) =================
    float (*pp)[4] = sm.k.pp;
    unsigned short* cs = sm.k.cs;
    const int bpc = NF/KQPB;
    const int b  = blockIdx.x / bpc;
    const int qb = blockIdx.x % bpc;

    {
        int e = blockIdx.x*192 + t;
        if (t < 192) out[(size_t)NFINE*COUT + e] = pos_skip[e];
        if (t >= 192 && t < 256) {
            int e2 = blockIdx.x*64 + (t - 192);
            out[(size_t)NFINE*COUT + (size_t)NFINE*3 + e2] = (float)(e2 >> 12);
        }
    }

    for (int i = t; i < NC; i += 512)
        *(f32x4*)&pp[i][0] = *(const f32x4*)&gp[(size_t)(b*NC + i)*4];
    for (int i = t; i < 513; i += 512) cs[i] = (unsigned short)gcs[b*513 + i];
    __syncthreads();

    const int g  = t & 7;
    const int ql = t >> 3;
    const int q  = b*NF + qb*KQPB + ql;
    const float qx = pos_skip[(size_t)q*3+0];
    const float qy = pos_skip[(size_t)q*3+1];
    const float qz = pos_skip[(size_t)q*3+2];
    const int cx = min(7, (int)(qx*8.0f));
    const int cy = min(7, (int)(qy*8.0f));
    const int cz = min(7, (int)(qz*8.0f));

    float d0 = 3.0e38f, dA = 3.0e38f, dB = 3.0e38f;
    int   i0 = 0,       iA = 0,       iB = 0;

    const int xlo = max(cx-1,0), xhi = min(cx+1,7);
    const int ylo = max(cy-1,0), yhi = min(cy+1,7);
    const int zlo = max(cz-1,0), zhi = min(cz+1,7);
    #pragma unroll
    for (int r = 0; r < 9; ++r) {
        const int z = cz - 1 + r/3;
        const int y = cy - 1 + r%3;
        const bool ok = ((unsigned)z < 8u) & ((unsigned)y < 8u);
        const int rb = (z*8 + y)*8;
        int js = 0, je = 0;
        if (ok) { js = cs[rb + xlo]; je = cs[rb + xhi + 1]; }
        SCAN(js, je);
    }
    MERGE8();

    float m1 = 3.0e38f;
    if (xlo > 0) m1 = fminf(m1, qx - xlo*0.125f);
    if (xhi < 7) m1 = fminf(m1, (xhi+1)*0.125f - qx);
    if (ylo > 0) m1 = fminf(m1, qy - ylo*0.125f);
    if (yhi < 7) m1 = fminf(m1, (yhi+1)*0.125f - qy);
    if (zlo > 0) m1 = fminf(m1, qz - zlo*0.125f);
    if (zhi < 7) m1 = fminf(m1, (zhi+1)*0.125f - qz);

    if (dB > m1*m1) {
        const float s0 = d0, s1 = dA, s2 = dB;
        const int   t0 = i0, t1 = iA, t2 = iB;
        d0 = dA = dB = 3.0e38f; i0 = iA = iB = 0;
        const int xlo2 = max(cx-2,0), xhi2 = min(cx+2,7);
        const int ylo2 = max(cy-2,0), yhi2 = min(cy+2,7);
        const int zlo2 = max(cz-2,0), zhi2 = min(cz+2,7);
        for (int z = zlo2; z <= zhi2; ++z)
        for (int y = ylo2; y <= yhi2; ++y) {
            const int rb = (z*8 + y)*8;
            const bool inner_zy = (z >= zlo && z <= zhi && y >= ylo && y <= yhi);
            int jsA, jeA, jsB, jeB;
            if (inner_zy) {
                jsA = cs[rb + xlo2]; jeA = cs[rb + xlo];
                jsB = cs[rb + xhi + 1]; jeB = cs[rb + xhi2 + 1];
            } else {
                jsA = cs[rb + xlo2]; jeA = cs[rb + xhi2 + 1];
                jsB = 0; jeB = 0;
            }
            SCAN(jsA, jeA);
            SCAN(jsB, jeB);
        }
        MERGE8();
        INS(s0, t0); INS(s1, t1); INS(s2, t2);

        float m2 = 3.0e38f;
        if (xlo2 > 0) m2 = fminf(m2, qx - xlo2*0.125f);
        if (xhi2 < 7) m2 = fminf(m2, (xhi2+1)*0.125f - qx);
        if (ylo2 > 0) m2 = fminf(m2, qy - ylo2*0.125f);
        if (yhi2 < 7) m2 = fminf(m2, (yhi2+1)*0.125f - qy);
        if (zlo2 > 0) m2 = fminf(m2, qz - zlo2*0.125f);
        if (zhi2 < 7) m2 = fminf(m2, (zhi2+1)*0.125f - qz);
        if (dB > m2*m2) {
            const float u0 = d0, u1 = dA, u2 = dB;
            const int   v0 = i0, v1 = iA, v2 = iB;
            d0 = dA = dB = 3.0e38f; i0 = iA = iB = 0;
            for (int j = g; j < NC; j += 8) {
                const f32x4 p = *(const f32x4*)&pp[j][0];
                int pcx = min(7, (int)(p[0]*8.0f));
                int pcy = min(7, (int)(p[1]*8.0f));
                int pcz = min(7, (int)(p[2]*8.0f));
                if (pcx >= xlo2 && pcx <= xhi2 && pcy >= ylo2 && pcy <= yhi2 &&
                    pcz >= zlo2 && pcz <= zhi2) continue;
                float fx = qx - p[0], fy = qy - p[1], fz = qz - p[2];
                float dd = fx*fx + fy*fy + fz*fz;
                INS(dd, j);
            }
            MERGE8();
            INS(u0, v0); INS(u1, v1); INS(u2, v2);
        }
    }

    if (g == 0) {
        const int o0 = __float_as_int(pp[i0][3]);
        const int o1 = __float_as_int(pp[iA][3]);
        const int o2 = __float_as_int(pp[iB][3]);
        float w0 = 1.0f / fmaxf(d0, 1e-16f);
        float w1 = 1.0f / fmaxf(dA, 1e-16f);
        float w2 = 1.0f / fmaxf(dB, 1e-16f);
        float inv = 1.0f / (w0 + w1 + w2);
        widx[q*3+0] = b*NC + o0;  wval[q*3+0] = w0*inv;
        widx[q*3+1] = b*NC + o1;  wval[q*3+1] = w1*inv;
        widx[q*3+2] = b*NC + o2;  wval[q*3+2] = w2*inv;
    }
}

// ---------------- g2_fused (r14-proven): 80KB LDS, 2 blocks/CU, 10 barriers ----------------
__global__ __launch_bounds__(512, 2)
void g2_fused(const float* __restrict__ x_skip,
              const float* __restrict__ b1,
              const __hip_bfloat16* __restrict__ Z,      // [NB*NC][CMID]
              const int* __restrict__ widx,
              const float* __restrict__ wval,
              const __hip_bfloat16* __restrict__ imgG,   // 2 step-images
              const __hip_bfloat16* __restrict__ img2,   // 4 step-images
              const float* __restrict__ b2,
              float* __restrict__ out)
{
    __shared__ __align__(16) short As[64][128];    // 16KB
    __shared__ __align__(16) short Bs[256][64];    // 32KB
    __shared__ __align__(16) short Hs[64][256];    // 32KB
    const int nwg = gridDim.x;                     // 1024 (%8==0)
    const int tile = (blockIdx.x & 7)*(nwg >> 3) + (blockIdx.x >> 3);
    const int m0 = tile * 64;

    const int t = threadIdx.x;
    const int wave = t >> 6, lane = t & 63;
    const int wm = wave >> 2, wn = wave & 3;
    const int rl = lane & 15, kq = lane >> 4;
    const short* gI = (const short*)imgG;
    const short* g2i = (const short*)img2;
    const short* Zr  = (const short*)Z;
    short* BsLin = &Bs[0][0];
    short (*BsH)[64] = (short(*)[64])&Hs[0][0];

    const int ar = t >> 3;        // 0..63
    const int ac = t & 7;

    const float* xs = &x_skip[(size_t)(m0+ar)*CSKIP];
    f32x4 pa0 = *(const f32x4*)&xs[ac*8];
    f32x4 pa1 = *(const f32x4*)&xs[ac*8+4];
    f32x4 pb0 = *(const f32x4*)&xs[64+ac*8];
    f32x4 pb1 = *(const f32x4*)&xs[64+ac*8+4];
    u32x4 rG0[4], rG1[4];
    #pragma unroll
    for (int i = 0; i < 4; ++i) {
        rG0[i] = *(const u32x4*)&gI[(size_t)(       i*512 + t)*8];
        rG1[i] = *(const u32x4*)&gI[(size_t)(2048 + i*512 + t)*8];
    }

    {
        short8 sv0, sv1;
        #pragma unroll
        for (int u = 0; u < 2; ++u) {
            f32x4 a = (u == 0) ? pa0 : pa1;
            f32x4 b = (u == 0) ? pb0 : pb1;
            #pragma unroll
            for (int e = 0; e < 4; ++e) {
                __hip_bfloat16 ba = __float2bfloat16(a[e]);
                __hip_bfloat16 bb = __float2bfloat16(b[e]);
                ((short*)&sv0)[u*4+e] = *(short*)&ba;
                ((short*)&sv1)[u*4+e] = *(short*)&bb;
            }
        }
        const int sw = ac ^ (ar & 7);
        *(short8*)&As[ar][sw*8]     = sv0;
        *(short8*)&As[ar][(8+sw)*8] = sv1;
    }
    #pragma unroll
    for (int i = 0; i < 4; ++i) {
        *(u32x4*)&BsLin[(size_t)(i*512 + t)*8]       = rG0[i];
        *(u32x4*)&(&Hs[0][0])[(size_t)(i*512 + t)*8] = rG1[i];
    }
    __syncthreads();   // [B1]

    f32x4 acc[2][4] = {};
    #pragma unroll
    for (int kh = 0; kh < 2; ++kh) {        // step 0 (Bs)
        const int kc = kh*4 + kq;
        short8 af[2], bf[4];
        #pragma unroll
        for (int mf = 0; mf < 2; ++mf)
            af[mf] = *(const short8*)&As[wm*32 + mf*16 + rl][((kc ^ (rl&7)))*8];
        #pragma unroll
        for (int nf = 0; nf < 4; ++nf)
            bf[nf] = *(const short8*)&Bs[wn*64 + nf*16 + rl][(kc ^ (rl&7))*8];
        #pragma unroll
        for (int mf = 0; mf < 2; ++mf)
        #pragma unroll
        for (int nf = 0; nf < 4; ++nf)
            acc[mf][nf] = __builtin_amdgcn_mfma_f32_16x16x32_bf16(af[mf], bf[nf], acc[mf][nf], 0,0,0);
    }
    #pragma unroll
    for (int kh = 0; kh < 2; ++kh) {        // step 1 (Hs region)
        const int kc = kh*4 + kq;
        short8 af[2], bf[4];
        #pragma unroll
        for (int mf = 0; mf < 2; ++mf)
            af[mf] = *(const short8*)&As[wm*32 + mf*16 + rl][(8 + (kc ^ (rl&7)))*8];
        #pragma unroll
        for (int nf = 0; nf < 4; ++nf)
            bf[nf] = *(const short8*)&BsH[wn*64 + nf*16 + rl][(kc ^ (rl&7))*8];
        #pragma unroll
        for (int mf = 0; mf < 2; ++mf)
        #pragma unroll
        for (int nf = 0; nf < 4; ++nf)
            acc[mf][nf] = __builtin_amdgcn_mfma_f32_16x16x32_bf16(af[mf], bf[nf], acc[mf][nf], 0,0,0);
    }
    __syncthreads();   // [B2]

    u32x4 rB[4];
    #pragma unroll
    for (int i = 0; i < 4; ++i)
        rB[i] = *(const u32x4*)&g2i[(size_t)(i*512 + t)*8];
    #pragma unroll
    for (int mf = 0; mf < 2; ++mf)
    #pragma unroll
    for (int nf = 0; nf < 4; ++nf) {
        const int col = wn*64 + nf*16 + rl;
        const float bv = b1[col];
        #pragma unroll
        for (int i = 0; i < 4; ++i) {
            const int row = wm*32 + mf*16 + kq*4 + i;
            float v = acc[mf][nf][i] + bv;
            __hip_bfloat16 bb = __float2bfloat16(v);
            Hs[row][((col >> 3) ^ (row & 7))*8 + (col & 7)] = *(short*)&bb;
        }
    }
    #pragma unroll
    for (int i = 0; i < 4; ++i)
        *(u32x4*)&BsLin[(size_t)(i*512 + t)*8] = rB[i];
    __syncthreads();   // [B3]

    #pragma unroll
    for (int u = 0; u < 4; ++u) {
        const int ch = t + u*512;
        const int row = ch >> 5;
        const int cc  = ch & 31;
        const int c   = cc * 8;
        const int gr = (m0 + row)*3;
        const int j0 = widx[gr+0], j1 = widx[gr+1], j2 = widx[gr+2];
        const float w0 = wval[gr+0], w1 = wval[gr+1], w2 = wval[gr+2];
        const short8 z0 = *(const short8*)&Zr[(size_t)j0*CMID + c];
        const short8 z1 = *(const short8*)&Zr[(size_t)j1*CMID + c];
        const short8 z2 = *(const short8*)&Zr[(size_t)j2*CMID + c];
        const int slot = (cc ^ (row & 7))*8;
        short8 gchunk = *(const short8*)&Hs[row][slot];
        short8 r;
        #pragma unroll
        for (int e = 0; e < 8; ++e) {
            float v = bf2f(gchunk[e]) + w0*bf2f(z0[e]) + w1*bf2f(z1[e]) + w2*bf2f(z2[e]);
            v = fmaxf(v, 0.0f);
            __hip_bfloat16 bb = __float2bfloat16(v);
            r[e] = *(short*)&bb;
        }
        *(short8*)&Hs[row][slot] = r;
    }
    __syncthreads();   // [B4]

    f32x4 acc2[2][4] = {};
    #define MFMA2(S2) do {                                                     \
        _Pragma("unroll")                                                      \
        for (int kh = 0; kh < 2; ++kh) {                                       \
            const int kcl = kh*4 + kq;                                         \
            const int kca = (S2)*8 + kcl;                                      \
            short8 af[2], bf[4];                                               \
            _Pragma("unroll")                                                  \
            for (int mf = 0; mf < 2; ++mf)                                     \
                af[mf] = *(const short8*)&Hs[wm*32 + mf*16 + rl][(kca ^ (rl&7))*8]; \
            _Pragma("unroll")                                                  \
            for (int nf = 0; nf < 4; ++nf)                                     \
                bf[nf] = *(const short8*)&Bs[wn*64 + nf*16 + rl][(kcl ^ (rl&7))*8]; \
            _Pragma("unroll")                                                  \
            for (int mf = 0; mf < 2; ++mf)                                     \
            _Pragma("unroll")                                                  \
            for (int nf = 0; nf < 4; ++nf)                                     \
                acc2[mf][nf] = __builtin_amdgcn_mfma_f32_16x16x32_bf16(af[mf], bf[nf], acc2[mf][nf], 0,0,0); \
        }                                                                      \
    } while (0)
    #define LOADI2(S) do {                                                     \
        _Pragma("unroll")                                                      \
        for (int i = 0; i < 4; ++i)                                            \
            rB[i] = *(const u32x4*)&g2i[(size_t)((S)*2048 + i*512 + t)*8];     \
    } while (0)
    #define STAGEI2() do {                                                     \
        _Pragma("unroll")                                                      \
        for (int i = 0; i < 4; ++i)                                            \
            *(u32x4*)&BsLin[(size_t)(i*512 + t)*8] = rB[i];                    \
    } while (0)

    LOADI2(1);
    MFMA2(0);
    __syncthreads();   // [B5]
    STAGEI2();
    __syncthreads();   // [B6]
    LOADI2(2);
    MFMA2(1);
    __syncthreads();   // [B7]
    STAGEI2();
    __syncthreads();   // [B8]
    LOADI2(3);
    MFMA2(2);
    __syncthreads();   // [B9]
    STAGEI2();
    __syncthreads();   // [B10]
    MFMA2(3);

    #pragma unroll
    for (int mf = 0; mf < 2; ++mf)
    #pragma unroll
    for (int nf = 0; nf < 4; ++nf) {
        const int col = wn*64 + nf*16 + rl;
        const float bv = b2[col];
        #pragma unroll
        for (int i = 0; i < 4; ++i) {
            const int row = m0 + wm*32 + mf*16 + kq*4 + i;
            out[(size_t)row*COUT + col] = fmaxf(acc2[mf][nf][i] + bv, 0.0f);
        }
    }
    #undef MFMA2
    #undef LOADI2
    #undef STAGEI2
}

extern "C" void kernel_launch(void* const* d_in, const int* in_sizes, int n_in,
                              void* d_out, int out_size, void* d_ws, size_t ws_size,
                              hipStream_t stream) {
    const float* x        = (const float*)d_in[0];
    const float* pos      = (const float*)d_in[1];
    const float* x_skip   = (const float*)d_in[4];
    const float* pos_skip = (const float*)d_in[5];
    const float* W1       = (const float*)d_in[8];
    const float* b1       = (const float*)d_in[9];
    const float* W2       = (const float*)d_in[10];
    const float* b2       = (const float*)d_in[11];
    float* out = (float*)d_out;
    char* ws = (char*)d_ws;

    int*            widx = (int*)  (ws + 0);                  //   786,432 B
    float*          wval = (float*)(ws + 786432);             //   786,432 B
    __hip_bfloat16* W1at = (__hip_bfloat16*)(ws + 1572864);   //   131,072 B
    __hip_bfloat16* imgG = (__hip_bfloat16*)(ws + 1703936);   //    65,536 B
    __hip_bfloat16* img2 = (__hip_bfloat16*)(ws + 1769472);   //   131,072 B
    float*          gp   = (float*)(ws + 1900544);            //   262,144 B
    int*            gcs  = (int*)  (ws + 2162688);            //    32,832 B (pad)
    __hip_bfloat16* Z    = (__hip_bfloat16*)(ws + 2195520);   // 8,388,608 B -> 10,584,128 total

    // launch 1: bin (16 blocks) + prep (640 blocks)
    hipLaunchKernelGGL(binprep_kernel, dim3(NB + 640), dim3(256), 0, stream,
                       pos, gp, gcs, W1, W2, W1at, imgG, img2);
    // launch 2: knn (1024 blocks) + gemmZ (256 blocks)
    hipLaunchKernelGGL(knnZ_kernel, dim3(1024 + 256), dim3(512), 0, stream,
                       pos_skip, gp, gcs, widx, wval, out, x, W1at, Z);
    // launch 3: fused MLP (r14-proven), 2 blocks/CU
    hipLaunchKernelGGL(g2_fused, dim3(NFINE/64), dim3(512), 0, stream,
                       x_skip, b1, Z, widx, wval, imgG, img2, b2, out);
}